// Round 9
// baseline (588.484 us; speedup 1.0000x reference)
//
#include <hip/hip_runtime.h>

typedef _Float16 f16;
typedef _Float16 f16x8 __attribute__((ext_vector_type(8)));
typedef _Float16 f16x4 __attribute__((ext_vector_type(4)));
typedef float f32x4 __attribute__((ext_vector_type(4)));

#define TD 512
#define TDH 2048

// tanh-form GELU: x * sigmoid(1.595769122*x + 0.0713548162*x^3)
__device__ __forceinline__ float gelu_fast(float x) {
  float u = x * fmaf(x * x, 0.0713548162f, 1.595769122f);
  float e = __expf(-u);
  return x * __builtin_amdgcn_rcpf(1.0f + e);
}

__device__ __forceinline__ void glds16(const f16* g, f16* l) {
  __builtin_amdgcn_global_load_lds(
      (const __attribute__((address_space(1))) void*)g,
      (__attribute__((address_space(3))) void*)l, 16, 0, 0);
}

__global__ __launch_bounds__(256) void k_conv_x(f16* __restrict__ dst,
                                                const float* __restrict__ src,
                                                int n4) {
  int i = blockIdx.x * 256 + threadIdx.x;
  if (i >= n4) return;
  float4 v = ((const float4*)src)[i];
  f16x4 o = {(f16)v.x, (f16)v.y, (f16)v.z, (f16)v.w};
  ((f16x4*)dst)[i] = o;
}

// Tiled transpose: dst[c*R + r] = src[r*C + c], both sides coalesced.
__global__ void k_trans(f16* __restrict__ dst, const float* __restrict__ src,
                        int R, int C) {
  __shared__ float t[32][33];
  const int bx = blockIdx.x, by = blockIdx.y;
  const int tx = threadIdx.x, ty = threadIdx.y;
#pragma unroll
  for (int s = 0; s < 32; s += 8)
    t[ty + s][tx] = src[(size_t)(by * 32 + ty + s) * C + bx * 32 + tx];
  __syncthreads();
#pragma unroll
  for (int s = 0; s < 32; s += 8)
    dst[(size_t)(bx * 32 + ty + s) * R + by * 32 + tx] = (f16)t[tx][ty + s];
}

// Writes wdT rows INTO B_ext at row offset 2048: B_ext[2048+n][k] for n<128.
__global__ __launch_bounds__(256) void k_wdT(f16* __restrict__ dst,
                                             const float* __restrict__ wd) {
  int i = blockIdx.x * 256 + threadIdx.x;  // 65536
  int n = i >> 9, k = i & 511;
  float v = (n < 24) ? wd[(size_t)((n >> 3) * 512 + k) * 8 + (n & 7)] : 0.0f;
  dst[i] = (f16)v;  // dst pre-offset to row 2048
}

// wuT64[512][64]: wuT64[d][er] = wu[er/8][er%8][d] for er<24 else 0
__global__ __launch_bounds__(256) void k_wuT(f16* __restrict__ dst,
                                             const float* __restrict__ wu) {
  int i = blockIdx.x * 256 + threadIdx.x;  // 32768
  int d = i >> 6, er = i & 63;
  float v = (er < 24) ? wu[(size_t)(er >> 3) * 4096 + (er & 7) * 512 + d] : 0.0f;
  dst[i] = (f16)v;
}

// ---------------------------------------------------------------------------
// 128x128 tile, BK=64, 4 waves (2x2), double-buffered LDS, early-issue STAGE.
// 32 MFMA + 16 ds_read_b128 per barrier-drain (2x the BK=32 amortization of
// the fixed ~1300-cyc drain latency measured in rounds 4-8; LDS 64KB keeps
// 2 blocks/CU so m132's occupancy regression doesn't apply).
// LDS [128][64] f16 per buffer; row = 128B = 32 banks, so slot swizzle is
// slot' = slot ^ (row&7) (8 16B-slots/row; balanced 8 lanes/bank-quad),
// applied on BOTH stage source and frag read (both-sides involution).
// Staging: thread covers region r = c*4+w (c=0..3), row 8r+(lane>>3),
// source slot (lane&7)^(lane>>3); dest = wave-uniform &buf[r*512] (+lane*16B).
// MFMA as mfma(bf, af): D reg axis = N -> vectorized epilogue stores.
// Grid 1D, XCD-chunked bijective swizzle (m204), bn-fast (A-panel L2 reuse).
// EPI 0 (N=2176 = W1T||wdT): bn<16 -> Hout=f16(gelu(acc+b1)); bn==16 ->
//        Gout[m][0..31] = topk_w * gelu(acc), [32..63] = 0  (K-pad for EPI1)
// EPI 1: Out = acc(32 main K-steps + 1 LoRA step from Ag,Bg) + bias
// ---------------------------------------------------------------------------
template <int EPI, int NBN>
__global__ __launch_bounds__(256) void k_gemm64(
    const f16* __restrict__ A, const f16* __restrict__ B, int NT, int ntm,
    int lda, int ldb, const float* __restrict__ bias, f16* __restrict__ Hout,
    int ldh, f16* __restrict__ Gout, float* __restrict__ Out, int ldc,
    const float* __restrict__ tkp, const int* __restrict__ tki,
    const f16* __restrict__ Ag, const f16* __restrict__ Bg) {
  __shared__ __align__(16) f16 As[2][128 * 64];
  __shared__ __align__(16) f16 Bs[2][128 * 64];
  const int tid = threadIdx.x;
  const int lane = tid & 63;
  const int w = tid >> 6;
  const int wm = w >> 1, wn = w & 1;

  // XCD-chunked bijective swizzle (m204); bn fastest within a chunk.
  const int nwg = gridDim.x;
  const int q = nwg >> 3, r = nwg & 7;
  const int xcd = blockIdx.x & 7, pos = blockIdx.x >> 3;
  const int swz =
      (xcd < r ? xcd * (q + 1) : r * (q + 1) + (xcd - r) * q) + pos;
  const int bm = swz / NBN, bn = swz % NBN;

  // staging addressing
  const int r0 = lane >> 3;        // row within 8-row region
  const int ssl = (lane & 7) ^ r0; // source 16B slot (swizzled)
  const f16* pA[4];
  const f16* pB[4];
  const f16* qA[4];
  const f16* qB[4];
#pragma unroll
  for (int c = 0; c < 4; c++) {
    const int rg = c * 4 + w;
    const int row = rg * 8 + r0;
    pA[c] = A + (size_t)(bm * 128 + row) * lda + ssl * 8;
    pB[c] = B + (size_t)(bn * 128 + row) * ldb + ssl * 8;
    if constexpr (EPI == 1) {
      qA[c] = Ag + (size_t)(bm * 128 + row) * 64 + ssl * 8;
      qB[c] = Bg + (size_t)(bn * 128 + row) * 64 + ssl * 8;
    }
  }

#define STAGE(S, BUF)                                                    \
  do {                                                                   \
    if (EPI == 1 && (S) == ntm) {                                        \
      _Pragma("unroll") for (int c = 0; c < 4; c++) {                    \
        glds16(qA[c], &As[BUF][(c * 4 + w) * 512]);                      \
        glds16(qB[c], &Bs[BUF][(c * 4 + w) * 512]);                      \
      }                                                                  \
    } else {                                                             \
      const size_t o = (size_t)(S) * 64;                                 \
      _Pragma("unroll") for (int c = 0; c < 4; c++) {                    \
        glds16(pA[c] + o, &As[BUF][(c * 4 + w) * 512]);                  \
        glds16(pB[c] + o, &Bs[BUF][(c * 4 + w) * 512]);                  \
      }                                                                  \
    }                                                                    \
  } while (0)

  f32x4 acc[4][4] = {};
  const int frow = lane & 15;
  const int fq = lane >> 4;
  const int fx = frow & 7;
  // two k-half slot offsets (f16 units), swizzled
  const int sA0 = ((fq ^ fx)) * 8;
  const int sA1 = (((4 | fq) ^ fx)) * 8;
  const int aRow = (wm * 64 + frow) * 64;
  const int bRow = (wn * 64 + frow) * 64;

  // prologue
  STAGE(0, 0);
  __syncthreads();

  for (int t = 0; t < NT; ++t) {
    if (t + 1 < NT) STAGE(t + 1, (t + 1) & 1);
    const f16* rA = As[t & 1];
    const f16* rB = Bs[t & 1];
    f16x8 af[4][2], bf[4][2];
#pragma unroll
    for (int i = 0; i < 4; i++) {
      af[i][0] = *(const f16x8*)&rA[aRow + i * 1024 + sA0];
      af[i][1] = *(const f16x8*)&rA[aRow + i * 1024 + sA1];
    }
#pragma unroll
    for (int j = 0; j < 4; j++) {
      bf[j][0] = *(const f16x8*)&rB[bRow + j * 1024 + sA0];
      bf[j][1] = *(const f16x8*)&rB[bRow + j * 1024 + sA1];
    }
#pragma unroll
    for (int i = 0; i < 4; i++)
#pragma unroll
      for (int j = 0; j < 4; j++) {
        acc[i][j] = __builtin_amdgcn_mfma_f32_16x16x32_f16(bf[j][0], af[i][0],
                                                           acc[i][j], 0, 0, 0);
        acc[i][j] = __builtin_amdgcn_mfma_f32_16x16x32_f16(bf[j][1], af[i][1],
                                                           acc[i][j], 0, 0, 0);
      }
    __syncthreads();
  }
#undef STAGE

  // D layout (swapped operands): m = wm*64 + i*16 + (lane&15),
  // n = wn*64 + j*16 + fq*4 + r
  const int m0 = wm * 64 + frow;
  const int n0 = wn * 64 + fq * 4;

  if constexpr (EPI == 0) {
    if (bn != NBN - 1) {  // H epilogue
#pragma unroll
      for (int i = 0; i < 4; i++) {
        const size_t rb =
            (size_t)(bm * 128 + m0 + i * 16) * ldh + bn * 128 + n0;
#pragma unroll
        for (int j = 0; j < 4; j++) {
          const float4 bb = *(const float4*)&bias[bn * 128 + n0 + j * 16];
          f16x4 o = {(f16)gelu_fast(acc[i][j][0] + bb.x),
                     (f16)gelu_fast(acc[i][j][1] + bb.y),
                     (f16)gelu_fast(acc[i][j][2] + bb.z),
                     (f16)gelu_fast(acc[i][j][3] + bb.w)};
          *(f16x4*)&Hout[rb + j * 16] = o;
        }
      }
    } else if (wn == 0) {  // g epilogue (LoRA-down), rows of Gout[m][64]
#pragma unroll
      for (int i = 0; i < 4; i++) {
        const int m = bm * 128 + m0 + i * 16;
        const int i0 = tki[m * 2], i1 = tki[m * 2 + 1];
        const float p0 = tkp[m * 2], p1 = tkp[m * 2 + 1];
#pragma unroll
        for (int j = 0; j < 4; j++) {
          const int nb = n0 + j * 16;  // 0..63
          f16x4 o;
          if (j < 2) {  // nb < 32: expert data
            const int e = nb >> 3;
            const float wgt = (i0 == e ? p0 : 0.0f) + (i1 == e ? p1 : 0.0f);
            o = f16x4{(f16)(wgt * gelu_fast(acc[i][j][0])),
                      (f16)(wgt * gelu_fast(acc[i][j][1])),
                      (f16)(wgt * gelu_fast(acc[i][j][2])),
                      (f16)(wgt * gelu_fast(acc[i][j][3]))};
          } else {  // K-pad zeros
            o = f16x4{(f16)0.f, (f16)0.f, (f16)0.f, (f16)0.f};
          }
          *(f16x4*)&Gout[(size_t)m * 64 + nb] = o;
        }
      }
    }
  } else {  // EPI 1: Out = acc + bias
#pragma unroll
    for (int i = 0; i < 4; i++) {
      const size_t rb = (size_t)(bm * 128 + m0 + i * 16) * ldc + bn * 128 + n0;
#pragma unroll
      for (int j = 0; j < 4; j++) {
        const float4 bb = *(const float4*)&bias[bn * 128 + n0 + j * 16];
        float4 v = {acc[i][j][0] + bb.x, acc[i][j][1] + bb.y,
                    acc[i][j][2] + bb.z, acc[i][j][3] + bb.w};
        *(float4*)&Out[rb + j * 16] = v;
      }
    }
  }
}

extern "C" void kernel_launch(void* const* d_in, const int* in_sizes, int n_in,
                              void* d_out, int out_size, void* d_ws,
                              size_t ws_size, hipStream_t stream) {
  const float* x = (const float*)d_in[0];
  const float* W1 = (const float*)d_in[1];
  const float* b1 = (const float*)d_in[2];
  const float* W2 = (const float*)d_in[3];
  const float* b2 = (const float*)d_in[4];
  const float* wd = (const float*)d_in[5];
  const float* wu = (const float*)d_in[6];
  const float* tkp = (const float*)d_in[8];
  const int* tki = (const int*)d_in[9];
  float* out = (float*)d_out;

  const int T = in_sizes[0] / TD;  // 50176

  char* p = (char*)d_ws;
  f16* W1Te = (f16*)p; p += (size_t)(TDH + 128) * TD * sizeof(f16);  // [2176][512]
  f16* W2T = (f16*)p; p += (size_t)TD * TDH * sizeof(f16);           // [512][2048]
  f16* wuT64 = (f16*)p; p += (size_t)TD * 64 * sizeof(f16);          // [512][64]
  size_t fixed = (size_t)(p - (char*)d_ws);
  const size_t per_tok = (size_t)(TD + TDH + 64) * sizeof(f16);
  long mc = (long)((ws_size > fixed ? ws_size - fixed : 0) / per_tok);
  if (mc > T) mc = T;
  mc = (mc / 128) * 128;
  if (mc < 128) mc = 128;
  f16* xb = (f16*)p; p += (size_t)mc * TD * sizeof(f16);
  f16* Hb = (f16*)p; p += (size_t)mc * TDH * sizeof(f16);
  f16* gb = (f16*)p;  // [mc][64]

  // B_ext rows 0..2047 = W1T; rows 2048..2175 = wdT (expert-padded)
  k_trans<<<dim3(TDH / 32, TD / 32), dim3(32, 8), 0, stream>>>(W1Te, W1, TD,
                                                               TDH);
  k_wdT<<<dim3(65536 / 256), 256, 0, stream>>>(W1Te + (size_t)TDH * TD, wd);
  k_trans<<<dim3(TD / 32, TDH / 32), dim3(32, 8), 0, stream>>>(W2T, W2, TDH,
                                                               TD);
  k_wuT<<<dim3(32768 / 256), 256, 0, stream>>>(wuT64, wu);

  for (long off = 0; off < T; off += mc) {
    long m = T - off;
    if (m > mc) m = mc;
    const int mt = (int)(m / 128);
    const int n4 = (int)(m * TD / 4);
    k_conv_x<<<dim3((n4 + 255) / 256), 256, 0, stream>>>(xb, x + off * TD, n4);
    // H = gelu(x @ W1T + b1)  AND  g = topk_w*gelu(x @ wdT) | 0   (K=512)
    k_gemm64<0, 17><<<dim3(mt * 17), 256, 0, stream>>>(
        xb, W1Te, TD / 64, TD / 64, TD, TD, b1, Hb, TDH, gb, nullptr, 0,
        tkp + off * 2, tki + off * 2, nullptr, nullptr);
    // out = H @ W2T + g @ wuT64 + b2   (32 main K-steps + 1 LoRA step)
    k_gemm64<1, 4><<<dim3(mt * 4), 256, 0, stream>>>(
        Hb, W2T, TDH / 64 + 1, TDH / 64, TDH, TDH, b2, nullptr, 0, nullptr,
        out + off * TD, TD, nullptr, nullptr, gb, wuT64);
  }
}